// Round 3
// baseline (184.659 us; speedup 1.0000x reference)
//
#include <hip/hip_runtime.h>
#include <hip/hip_bf16.h>

#define HDIM 1024
#define SEQ 2048
#define BATCH 16
#define M_TOT (SEQ*BATCH)   // 32768
#define NBLK 8              // N split into 8 chunks of 128
#define BM 128
#define BN 128
#define BK 32
#define NKT (HDIM/BK)       // 32

typedef __attribute__((ext_vector_type(8))) short short8;
typedef __attribute__((ext_vector_type(4))) float f32x4;

typedef const void __attribute__((address_space(1))) gvoid_t;
typedef void __attribute__((address_space(3))) svoid_t;
#define GLD16(gp, lp) __builtin_amdgcn_global_load_lds((gvoid_t*)(gp), (svoid_t*)(lp), 16, 0, 0)

static __device__ __forceinline__ unsigned short f2bf(float f) {
    unsigned int x = __float_as_uint(f);
    unsigned int r = (x + 0x7FFFu + ((x >> 16) & 1u)) >> 16;  // RNE
    return (unsigned short)r;
}

// ---------------- kernel 1: q[b][k] = sum_h hidden[b][h]*Wh[k][h] + attn_b[k] ----------------
__global__ __launch_bounds__(256) void qk_kernel(const float* __restrict__ hidden,
                                                 const float* __restrict__ attn_w,
                                                 const float* __restrict__ attn_b,
                                                 float* __restrict__ q) {
    int k = blockIdx.x;               // 0..1023
    int tid = threadIdx.x;            // 256
    const float* w = attn_w + (size_t)k * (2 * HDIM);  // Wh row k
    float p[BATCH];
#pragma unroll
    for (int b = 0; b < BATCH; b++) p[b] = 0.f;
    for (int h = tid; h < HDIM; h += 256) {
        float wv = w[h];
#pragma unroll
        for (int b = 0; b < BATCH; b++) p[b] += hidden[b * HDIM + h] * wv;
    }
#pragma unroll
    for (int b = 0; b < BATCH; b++) {
        for (int off = 32; off; off >>= 1) p[b] += __shfl_down(p[b], off);
    }
    __shared__ float red[4][BATCH];
    int lane = tid & 63, wid = tid >> 6;
    if (lane == 0) {
#pragma unroll
        for (int b = 0; b < BATCH; b++) red[wid][b] = p[b];
    }
    __syncthreads();
    if (tid < BATCH) {
        float s = red[0][tid] + red[1][tid] + red[2][tid] + red[3][tid] + attn_b[k];
        q[(size_t)tid * HDIM + k] = s;   // q[b][k]
    }
}

// ---------------- kernel 2: We fp32 -> bf16, layout web[n][h] ----------------
__global__ __launch_bounds__(256) void conv_kernel(const float* __restrict__ attn_w,
                                                   __hip_bfloat16* __restrict__ web) {
    size_t i0 = ((size_t)blockIdx.x * 256 + threadIdx.x) * 8;
    int n = (int)(i0 >> 10);
    int h = (int)(i0 & 1023);
    const float4* src = reinterpret_cast<const float4*>(attn_w + (size_t)n * (2 * HDIM) + HDIM + h);
    float4 a = src[0], b = src[1];
    union { unsigned short u[8]; short8 v; } cv;
    cv.u[0] = f2bf(a.x); cv.u[1] = f2bf(a.y); cv.u[2] = f2bf(a.z); cv.u[3] = f2bf(a.w);
    cv.u[4] = f2bf(b.x); cv.u[5] = f2bf(b.y); cv.u[6] = f2bf(b.z); cv.u[7] = f2bf(b.w);
    *reinterpret_cast<short8*>((unsigned short*)web + i0) = cv.v;
}

// ---------------- kernel 3: GEMM (A=fp32 reg-staged+cvt, B=bf16 gload_lds) + fused epilogue ----
// C[m][k] = sum_h enc[m][h]*We[k][h]; part[bn][m] = sum_{k in chunk} score_w[k]*tanh(q[b][k]+C[m][k])
__global__ __launch_bounds__(256) void gemm_bf(const float* __restrict__ enc,
                                               const __hip_bfloat16* __restrict__ web,
                                               const float* __restrict__ q,
                                               const float* __restrict__ score_w,
                                               float* __restrict__ part) {
    // As[2][128*32] bf16 (16KB) + Bs[2][128*32] bf16 (16KB); red[128][33] f32 aliases them
    __shared__ __align__(16) char pool[2 * BM * BK * 2 * 2];
    __hip_bfloat16 (*As)[BM * BK] = reinterpret_cast<__hip_bfloat16 (*)[BM * BK]>(pool);
    __hip_bfloat16 (*Bs)[BM * BK] = reinterpret_cast<__hip_bfloat16 (*)[BM * BK]>(pool + 2 * BM * BK * 2);
    float* red = reinterpret_cast<float*>(pool);       // [BM][33], 16896 B <= 32768
    __shared__ float q_lds[BATCH][BN];
    __shared__ float sc_lds[BN];

    int tid = threadIdx.x;
    int lane = tid & 63;
    int wid = tid >> 6;
    int wr = wid >> 1, wc = wid & 1;

    // XCD-aware decode: XCD x owns bm in [x*32, x*32+32), bn fastest -> same-panel blocks share L2
    int bid = blockIdx.x;
    int xcd = bid & 7;
    int lid = bid >> 3;          // 0..255
    int bn = lid & 7;            // 0..7
    int bm = xcd * 32 + (lid >> 3);
    int m0 = bm * BM, n0 = bn * BN;

    // A staging (fp32 source): thread covers row tid>>1, 16 cols at (tid&1)*16
    int srowA = tid >> 1;
    int shalfA = tid & 1;
    const float* gA = enc + (size_t)(m0 + srowA) * HDIM + shalfA * 16;

    // B staging via global_load_lds: wave wid covers rows [wid*32, wid*32+32)
    int srowB = wid * 32 + (lane >> 2);
    int scolB = (lane & 3) * 8;
    const __hip_bfloat16* gB = web + (size_t)(n0 + srowB) * HDIM + scolB;
    unsigned lo = wid * 1024;  // element offset of this wave's LDS chunk

    float4 a0, a1, a2, a3;
    f32x4 acc[4][4];
#pragma unroll
    for (int i = 0; i < 4; i++)
#pragma unroll
        for (int j = 0; j < 4; j++) acc[i][j] = (f32x4)0.f;

    auto ALOAD = [&](int kt) {
        const float4* pa = reinterpret_cast<const float4*>(gA + kt * BK);
        a0 = pa[0]; a1 = pa[1]; a2 = pa[2]; a3 = pa[3];
    };
    auto ASTORE = [&](int buf) {
        union { __hip_bfloat162 h[4]; short8 v; } u0, u1;
        u0.h[0] = __float22bfloat162_rn(make_float2(a0.x, a0.y));
        u0.h[1] = __float22bfloat162_rn(make_float2(a0.z, a0.w));
        u0.h[2] = __float22bfloat162_rn(make_float2(a1.x, a1.y));
        u0.h[3] = __float22bfloat162_rn(make_float2(a1.z, a1.w));
        u1.h[0] = __float22bfloat162_rn(make_float2(a2.x, a2.y));
        u1.h[1] = __float22bfloat162_rn(make_float2(a2.z, a2.w));
        u1.h[2] = __float22bfloat162_rn(make_float2(a3.x, a3.y));
        u1.h[3] = __float22bfloat162_rn(make_float2(a3.z, a3.w));
        __hip_bfloat16* da = &As[buf][srowA * BK + shalfA * 16];
        *reinterpret_cast<short8*>(da) = u0.v;
        *reinterpret_cast<short8*>(da + 8) = u1.v;
    };
    auto BLOAD = [&](int buf, int kt) {
        const __hip_bfloat16* pb = gB + kt * BK;
        GLD16(pb, &Bs[buf][lo]);
        GLD16(pb + 16 * HDIM, &Bs[buf][lo + 512]);
    };

    auto COMPUTE = [&](int buf) {
        short8 af[4], bfr[4];
        int rA = wr * 64 + (lane & 15);
        int rB = wc * 64 + (lane & 15);
        int ko = (lane >> 4) * 8;
#pragma unroll
        for (int i = 0; i < 4; i++) af[i] = *reinterpret_cast<const short8*>(&As[buf][(rA + i * 16) * BK + ko]);
#pragma unroll
        for (int j = 0; j < 4; j++) bfr[j] = *reinterpret_cast<const short8*>(&Bs[buf][(rB + j * 16) * BK + ko]);
#pragma unroll
        for (int i = 0; i < 4; i++)
#pragma unroll
            for (int j = 0; j < 4; j++)
                acc[i][j] = __builtin_amdgcn_mfma_f32_16x16x32_bf16(af[i], bfr[j], acc[i][j], 0, 0, 0);
    };

    ALOAD(0);
    BLOAD(0, 0);
    ASTORE(0);
    __syncthreads();
    for (int kt = 0; kt < NKT; ++kt) {
        int cur = kt & 1;
        if (kt + 1 < NKT) { ALOAD(kt + 1); BLOAD(cur ^ 1, kt + 1); }
        COMPUTE(cur);
        if (kt + 1 < NKT) ASTORE(cur ^ 1);
        __syncthreads();
    }

    // epilogue: stage q-slice and score-slice
    {
        int idx = tid * 8;            // 0..2047
        int qb = idx >> 7, kl = idx & 127;
        const float4* src = reinterpret_cast<const float4*>(q + (size_t)qb * HDIM + n0 + kl);
        float4 v0 = src[0], v1 = src[1];
        *reinterpret_cast<float4*>(&q_lds[qb][kl]) = v0;
        *reinterpret_cast<float4*>(&q_lds[qb][kl + 4]) = v1;
        if (tid < BN) sc_lds[tid] = score_w[n0 + tid];
    }
    __syncthreads();

    // per-thread partials (sum over this thread's 4 k-cols), write to red[row][wc*16+c]
    int c = lane & 15, cs = lane >> 4;
#pragma unroll
    for (int mi = 0; mi < 4; ++mi) {
#pragma unroll
        for (int r = 0; r < 4; ++r) {
            int b = cs * 4 + r;  // row-within-16 == batch index (M = s*16 + b)
            float s = 0.f;
#pragma unroll
            for (int j = 0; j < 4; ++j) {
                int kl = wc * 64 + j * 16 + c;
                float v = acc[mi][j][r] + q_lds[b][kl];
                float t = 1.f - 2.f / (__expf(2.f * v) + 1.f);  // tanh(v)
                s += sc_lds[kl] * t;
            }
            int row = wr * 64 + mi * 16 + b;
            red[row * 33 + wc * 16 + c] = s;
        }
    }
    __syncthreads();
    if (tid < BM) {
        float s = 0.f;
#pragma unroll
        for (int i = 0; i < 32; ++i) s += red[tid * 33 + i];
        part[(size_t)bn * M_TOT + m0 + tid] = s;
    }
}

// ---------------- kernel 4: reduce partials + mask + softmax over S ----------------
__global__ __launch_bounds__(256) void softmax_kernel(const float* __restrict__ part,
                                                      const int* __restrict__ mask,
                                                      float* __restrict__ out) {
    int b = blockIdx.x;
    int tid = threadIdx.x;
    __shared__ float e_lds[SEQ];
    __shared__ float red[4], red2[4];
    int lane = tid & 63, wid = tid >> 6;
    float lmax = -3.4e38f;
    for (int it = 0; it < SEQ / 256; ++it) {
        int s = it * 256 + tid;
        size_t m = (size_t)s * BATCH + b;
        float e = 0.f;
#pragma unroll
        for (int c = 0; c < NBLK; c++) e += part[(size_t)c * M_TOT + m];
        if (mask[(size_t)b * SEQ + s]) e = -1e12f;
        e_lds[s] = e;
        lmax = fmaxf(lmax, e);
    }
    for (int off = 32; off; off >>= 1) lmax = fmaxf(lmax, __shfl_xor(lmax, off));
    if (lane == 0) red[wid] = lmax;
    __syncthreads();
    float gmax = fmaxf(fmaxf(red[0], red[1]), fmaxf(red[2], red[3]));
    float lsum = 0.f;
    for (int it = 0; it < SEQ / 256; ++it) {
        int s = it * 256 + tid;
        float p = __expf(e_lds[s] - gmax);
        e_lds[s] = p;
        lsum += p;
    }
    for (int off = 32; off; off >>= 1) lsum += __shfl_xor(lsum, off);
    if (lane == 0) red2[wid] = lsum;
    __syncthreads();
    float inv = 1.f / (red2[0] + red2[1] + red2[2] + red2[3]);
    for (int it = 0; it < SEQ / 256; ++it) {
        int s = it * 256 + tid;
        out[(size_t)b * SEQ + s] = e_lds[s] * inv;
    }
}

extern "C" void kernel_launch(void* const* d_in, const int* in_sizes, int n_in,
                              void* d_out, int out_size, void* d_ws, size_t ws_size,
                              hipStream_t stream) {
    const float* hidden   = (const float*)d_in[0];
    const float* enc      = (const float*)d_in[1];
    const int*   seq_mask = (const int*)d_in[2];
    const float* attn_w   = (const float*)d_in[3];
    const float* attn_b   = (const float*)d_in[4];
    const float* score_w  = (const float*)d_in[5];
    float* out = (float*)d_out;

    char* ws = (char*)d_ws;
    float* q = (float*)ws;                                        // 64 KB
    __hip_bfloat16* web = (__hip_bfloat16*)(ws + 65536);          // 2 MB
    float* part = (float*)(ws + 65536 + 2 * 1024 * 1024);         // 1 MB

    conv_kernel<<<dim3((HDIM * HDIM) / (8 * 256)), dim3(256), 0, stream>>>(attn_w, web);
    qk_kernel<<<dim3(HDIM), dim3(256), 0, stream>>>(hidden, attn_w, attn_b, q);
    gemm_bf<<<dim3(NBLK * M_TOT / BM), dim3(256), 0, stream>>>(enc, web, q, score_w, part);
    softmax_kernel<<<dim3(BATCH), dim3(256), 0, stream>>>(part, seq_mask, out);
}

// Round 4
// 130.528 us; speedup vs baseline: 1.4147x; 1.4147x over previous
//
#include <hip/hip_runtime.h>
#include <hip/hip_bf16.h>

#define HDIM 1024
#define SEQ 2048
#define BATCH 16
#define M_TOT (SEQ*BATCH)   // 32768
#define NBLK 4              // N split into 4 chunks of 256
#define BM 128
#define BN 256
#define BK 32
#define NKT (HDIM/BK)       // 32

typedef __attribute__((ext_vector_type(8))) short short8;
typedef __attribute__((ext_vector_type(4))) float f32x4;

typedef const void __attribute__((address_space(1))) gvoid_t;
typedef void __attribute__((address_space(3))) svoid_t;
#define GLD16(gp, lp) __builtin_amdgcn_global_load_lds((gvoid_t*)(gp), (svoid_t*)(lp), 16, 0, 0)

static __device__ __forceinline__ unsigned short f2bf(float f) {
    unsigned int x = __float_as_uint(f);
    unsigned int r = (x + 0x7FFFu + ((x >> 16) & 1u)) >> 16;  // RNE
    return (unsigned short)r;
}

// ---------------- kernel 1: q[b][k] = sum_h hidden[b][h]*Wh[k][h] + attn_b[k] ----------------
__global__ __launch_bounds__(256) void qk_kernel(const float* __restrict__ hidden,
                                                 const float* __restrict__ attn_w,
                                                 const float* __restrict__ attn_b,
                                                 float* __restrict__ q) {
    int k = blockIdx.x;               // 0..1023
    int tid = threadIdx.x;            // 256
    const float* w = attn_w + (size_t)k * (2 * HDIM);  // Wh row k
    float p[BATCH];
#pragma unroll
    for (int b = 0; b < BATCH; b++) p[b] = 0.f;
    for (int h = tid; h < HDIM; h += 256) {
        float wv = w[h];
#pragma unroll
        for (int b = 0; b < BATCH; b++) p[b] += hidden[b * HDIM + h] * wv;
    }
#pragma unroll
    for (int b = 0; b < BATCH; b++) {
        for (int off = 32; off; off >>= 1) p[b] += __shfl_down(p[b], off);
    }
    __shared__ float red[4][BATCH];
    int lane = tid & 63, wid = tid >> 6;
    if (lane == 0) {
#pragma unroll
        for (int b = 0; b < BATCH; b++) red[wid][b] = p[b];
    }
    __syncthreads();
    if (tid < BATCH) {
        float s = red[0][tid] + red[1][tid] + red[2][tid] + red[3][tid] + attn_b[k];
        q[(size_t)tid * HDIM + k] = s;   // q[b][k]
    }
}

// ---------------- kernel 2: We fp32 -> bf16, layout web[n][h] ----------------
__global__ __launch_bounds__(256) void conv_kernel(const float* __restrict__ attn_w,
                                                   __hip_bfloat16* __restrict__ web) {
    size_t i0 = ((size_t)blockIdx.x * 256 + threadIdx.x) * 8;
    int n = (int)(i0 >> 10);
    int h = (int)(i0 & 1023);
    const float4* src = reinterpret_cast<const float4*>(attn_w + (size_t)n * (2 * HDIM) + HDIM + h);
    float4 a = src[0], b = src[1];
    union { unsigned short u[8]; short8 v; } cv;
    cv.u[0] = f2bf(a.x); cv.u[1] = f2bf(a.y); cv.u[2] = f2bf(a.z); cv.u[3] = f2bf(a.w);
    cv.u[4] = f2bf(b.x); cv.u[5] = f2bf(b.y); cv.u[6] = f2bf(b.z); cv.u[7] = f2bf(b.w);
    *reinterpret_cast<short8*>((unsigned short*)web + i0) = cv.v;
}

// ---------------- kernel 2b: enc fp32 -> bf16 (row-major [M_TOT][H]) ----------------
__global__ __launch_bounds__(256) void conv_enc(const float* __restrict__ src,
                                                __hip_bfloat16* __restrict__ dst) {
    size_t i0 = ((size_t)blockIdx.x * 256 + threadIdx.x) * 8;
    const float4* s = reinterpret_cast<const float4*>(src + i0);
    float4 a = s[0], b = s[1];
    union { unsigned short u[8]; short8 v; } cv;
    cv.u[0] = f2bf(a.x); cv.u[1] = f2bf(a.y); cv.u[2] = f2bf(a.z); cv.u[3] = f2bf(a.w);
    cv.u[4] = f2bf(b.x); cv.u[5] = f2bf(b.y); cv.u[6] = f2bf(b.z); cv.u[7] = f2bf(b.w);
    *reinterpret_cast<short8*>((unsigned short*)dst + i0) = cv.v;
}

// ---------------- kernel 3: bf16 GEMM 128x256, 8 waves, gload_lds staging + fused epilogue ----
// C[m][k] = sum_h enc[m][h]*We[k][h]; part[bn][m] = sum_{k in chunk} score_w[k]*tanh(q[b][k]+C[m][k])
__global__ __launch_bounds__(512, 4) void gemm_bf(const __hip_bfloat16* __restrict__ encb,
                                                  const __hip_bfloat16* __restrict__ web,
                                                  const float* __restrict__ q,
                                                  const float* __restrict__ score_w,
                                                  float* __restrict__ part) {
    // staging pool: As[2][128*32] bf16 (16KB) + Bs[2][256*32] bf16 (32KB) = 48KB
    // epilogue aliases it: q_lds[16][256] f32 (16KB) + sc[256] (1KB) + eng[4][128] (2KB)
    __shared__ __align__(16) char pool[49152];
    __hip_bfloat16 (*As)[BM * BK] = reinterpret_cast<__hip_bfloat16 (*)[BM * BK]>(pool);
    __hip_bfloat16 (*Bs)[BN * BK] = reinterpret_cast<__hip_bfloat16 (*)[BN * BK]>(pool + 16384);
    float* q_lds = reinterpret_cast<float*>(pool);            // [16][256]
    float* sc_lds = reinterpret_cast<float*>(pool + 16384);   // [256]
    float* eng = reinterpret_cast<float*>(pool + 17408);      // [4][128]

    int tid = threadIdx.x;
    int lane = tid & 63;
    int wid = tid >> 6;           // 0..7
    int wr = wid >> 2;            // 0..1  (M half: wr*64)
    int wc = wid & 3;             // 0..3  (N quarter: wc*64)
    int bn = blockIdx.x, bm = blockIdx.y;
    int m0 = bm * BM, n0 = bn * BN;

    // staging: thread covers row tid>>2, 8-elem seg (tid&3)*8; wave-uniform LDS bases
    int srow = tid >> 2;          // 0..127
    int scol = (tid & 3) * 8;
    const __hip_bfloat16* gA = encb + (size_t)(m0 + srow) * HDIM + scol;
    const __hip_bfloat16* gB0 = web + (size_t)(n0 + srow) * HDIM + scol;
    const __hip_bfloat16* gB1 = web + (size_t)(n0 + 128 + srow) * HDIM + scol;
    unsigned loA = wid * 512;     // wave chunk: 16 rows * 32 elems
    unsigned loB0 = wid * 512;
    unsigned loB1 = 4096 + wid * 512;

    f32x4 acc[4][4];
#pragma unroll
    for (int i = 0; i < 4; i++)
#pragma unroll
        for (int j = 0; j < 4; j++) acc[i][j] = (f32x4)0.f;

    auto STAGE = [&](int buf, int kt) {
        GLD16(gA + kt * BK, &As[buf][loA]);
        GLD16(gB0 + kt * BK, &Bs[buf][loB0]);
        GLD16(gB1 + kt * BK, &Bs[buf][loB1]);
    };

    auto COMPUTE = [&](int buf) {
        short8 af[4], bfr[4];
        int rA = wr * 64 + (lane & 15);
        int rB = wc * 64 + (lane & 15);
        int ko = (lane >> 4) * 8;
#pragma unroll
        for (int i = 0; i < 4; i++) af[i] = *reinterpret_cast<const short8*>(&As[buf][(rA + i * 16) * BK + ko]);
#pragma unroll
        for (int j = 0; j < 4; j++) bfr[j] = *reinterpret_cast<const short8*>(&Bs[buf][(rB + j * 16) * BK + ko]);
#pragma unroll
        for (int i = 0; i < 4; i++)
#pragma unroll
            for (int j = 0; j < 4; j++)
                acc[i][j] = __builtin_amdgcn_mfma_f32_16x16x32_bf16(af[i], bfr[j], acc[i][j], 0, 0, 0);
    };

    STAGE(0, 0);
    __syncthreads();
    for (int kt = 0; kt < NKT; ++kt) {
        int cur = kt & 1;
        if (kt + 1 < NKT) STAGE(cur ^ 1, kt + 1);
        COMPUTE(cur);
        __syncthreads();
    }

    // epilogue (aliases staging pool; safe after the barrier above)
    {
        int idx = tid * 8;            // 0..4095
        int qb = idx >> 8;            // 0..15
        int kl = idx & 255;
        const float4* src = reinterpret_cast<const float4*>(q + (size_t)qb * HDIM + n0 + kl);
        float4 v0 = src[0], v1 = src[1];
        *reinterpret_cast<float4*>(&q_lds[qb * 256 + kl]) = v0;
        *reinterpret_cast<float4*>(&q_lds[qb * 256 + kl + 4]) = v1;
        if (tid < BN) sc_lds[tid] = score_w[n0 + tid];
    }
    __syncthreads();

    int c = lane & 15, cs = lane >> 4;
#pragma unroll
    for (int mi = 0; mi < 4; ++mi) {
#pragma unroll
        for (int r = 0; r < 4; ++r) {
            int b = cs * 4 + r;  // row-within-16 == batch index (M = s*16 + b)
            float s = 0.f;
#pragma unroll
            for (int j = 0; j < 4; ++j) {
                int kl = wc * 64 + j * 16 + c;
                float v = acc[mi][j][r] + q_lds[b * 256 + kl];
                float t = 1.f - 2.f / (__expf(2.f * v) + 1.f);  // tanh(v)
                s += sc_lds[kl] * t;
            }
            for (int off = 1; off < 16; off <<= 1) s += __shfl_xor(s, off);
            if (c == 0) eng[wc * 128 + wr * 64 + mi * 16 + b] = s;
        }
    }
    __syncthreads();
    if (tid < BM) {
        float s = eng[tid] + eng[128 + tid] + eng[256 + tid] + eng[384 + tid];
        part[(size_t)bn * M_TOT + m0 + tid] = s;
    }
}

// ---------------- kernel 4: reduce partials + mask + softmax over S ----------------
__global__ __launch_bounds__(256) void softmax_kernel(const float* __restrict__ part,
                                                      const int* __restrict__ mask,
                                                      float* __restrict__ out) {
    int b = blockIdx.x;
    int tid = threadIdx.x;
    __shared__ float e_lds[SEQ];
    __shared__ float red[4], red2[4];
    int lane = tid & 63, wid = tid >> 6;
    float lmax = -3.4e38f;
    for (int it = 0; it < SEQ / 256; ++it) {
        int s = it * 256 + tid;
        size_t m = (size_t)s * BATCH + b;
        float e = 0.f;
#pragma unroll
        for (int c = 0; c < NBLK; c++) e += part[(size_t)c * M_TOT + m];
        if (mask[(size_t)b * SEQ + s]) e = -1e12f;
        e_lds[s] = e;
        lmax = fmaxf(lmax, e);
    }
    for (int off = 32; off; off >>= 1) lmax = fmaxf(lmax, __shfl_xor(lmax, off));
    if (lane == 0) red[wid] = lmax;
    __syncthreads();
    float gmax = fmaxf(fmaxf(red[0], red[1]), fmaxf(red[2], red[3]));
    float lsum = 0.f;
    for (int it = 0; it < SEQ / 256; ++it) {
        int s = it * 256 + tid;
        float p = __expf(e_lds[s] - gmax);
        e_lds[s] = p;
        lsum += p;
    }
    for (int off = 32; off; off >>= 1) lsum += __shfl_xor(lsum, off);
    if (lane == 0) red2[wid] = lsum;
    __syncthreads();
    float inv = 1.f / (red2[0] + red2[1] + red2[2] + red2[3]);
    for (int it = 0; it < SEQ / 256; ++it) {
        int s = it * 256 + tid;
        out[(size_t)b * SEQ + s] = e_lds[s] * inv;
    }
}

extern "C" void kernel_launch(void* const* d_in, const int* in_sizes, int n_in,
                              void* d_out, int out_size, void* d_ws, size_t ws_size,
                              hipStream_t stream) {
    const float* hidden   = (const float*)d_in[0];
    const float* enc      = (const float*)d_in[1];
    const int*   seq_mask = (const int*)d_in[2];
    const float* attn_w   = (const float*)d_in[3];
    const float* attn_b   = (const float*)d_in[4];
    const float* score_w  = (const float*)d_in[5];
    float* out = (float*)d_out;

    char* ws = (char*)d_ws;
    float* q = (float*)ws;                                        // 64 KB
    __hip_bfloat16* web = (__hip_bfloat16*)(ws + 65536);          // 2 MB
    float* part = (float*)(ws + 65536 + 2 * 1024 * 1024);         // 512 KB
    __hip_bfloat16* encb = (__hip_bfloat16*)(ws + 65536 + 3 * 1024 * 1024);  // 64 MB

    conv_enc<<<dim3((M_TOT * HDIM) / (8 * 256)), dim3(256), 0, stream>>>(enc, encb);
    conv_kernel<<<dim3((HDIM * HDIM) / (8 * 256)), dim3(256), 0, stream>>>(attn_w, web);
    qk_kernel<<<dim3(HDIM), dim3(256), 0, stream>>>(hidden, attn_w, attn_b, q);
    gemm_bf<<<dim3(NBLK, M_TOT / BM), dim3(512), 0, stream>>>(encb, web, q, score_w, part);
    softmax_kernel<<<dim3(BATCH), dim3(256), 0, stream>>>(part, seq_mask, out);
}

// Round 5
// 121.690 us; speedup vs baseline: 1.5175x; 1.0726x over previous
//
#include <hip/hip_runtime.h>
#include <hip/hip_bf16.h>

#define HDIM 1024
#define SEQ 2048
#define BATCH 16
#define M_TOT (SEQ*BATCH)   // 32768
#define NBLK 4              // N split into 4 chunks of 256
#define BM 256
#define BN 256
#define BKT 64              // K-tile depth
#define NT (HDIM/BKT)       // 16 K-tiles

typedef __attribute__((ext_vector_type(8))) short short8;
typedef __attribute__((ext_vector_type(4))) float f32x4;

typedef const void __attribute__((address_space(1))) gvoid_t;
typedef void __attribute__((address_space(3))) svoid_t;
#define GLD16(gp, lp) __builtin_amdgcn_global_load_lds((gvoid_t*)(gp), (svoid_t*)(lp), 16, 0, 0)
#define VMC(N) asm volatile("s_waitcnt vmcnt(" #N ")" ::: "memory")

static __device__ __forceinline__ unsigned short f2bf(float f) {
    unsigned int x = __float_as_uint(f);
    unsigned int r = (x + 0x7FFFu + ((x >> 16) & 1u)) >> 16;  // RNE
    return (unsigned short)r;
}

// ---------------- kernel 1: q[b][k] = sum_h hidden[b][h]*Wh[k][h] + attn_b[k] ----------------
__global__ __launch_bounds__(256) void qk_kernel(const float* __restrict__ hidden,
                                                 const float* __restrict__ attn_w,
                                                 const float* __restrict__ attn_b,
                                                 float* __restrict__ q) {
    int k = blockIdx.x;
    int tid = threadIdx.x;
    const float* w = attn_w + (size_t)k * (2 * HDIM);
    float p[BATCH];
#pragma unroll
    for (int b = 0; b < BATCH; b++) p[b] = 0.f;
    for (int h = tid; h < HDIM; h += 256) {
        float wv = w[h];
#pragma unroll
        for (int b = 0; b < BATCH; b++) p[b] += hidden[b * HDIM + h] * wv;
    }
#pragma unroll
    for (int b = 0; b < BATCH; b++) {
        for (int off = 32; off; off >>= 1) p[b] += __shfl_down(p[b], off);
    }
    __shared__ float red[4][BATCH];
    int lane = tid & 63, wid = tid >> 6;
    if (lane == 0) {
#pragma unroll
        for (int b = 0; b < BATCH; b++) red[wid][b] = p[b];
    }
    __syncthreads();
    if (tid < BATCH) {
        float s = red[0][tid] + red[1][tid] + red[2][tid] + red[3][tid] + attn_b[k];
        q[(size_t)tid * HDIM + k] = s;
    }
}

// ---------------- kernel 2: We fp32 -> bf16, layout web[n][h] ----------------
__global__ __launch_bounds__(256) void conv_kernel(const float* __restrict__ attn_w,
                                                   __hip_bfloat16* __restrict__ web) {
    size_t i0 = ((size_t)blockIdx.x * 256 + threadIdx.x) * 8;
    int n = (int)(i0 >> 10);
    int h = (int)(i0 & 1023);
    const float4* src = reinterpret_cast<const float4*>(attn_w + (size_t)n * (2 * HDIM) + HDIM + h);
    float4 a = src[0], b = src[1];
    union { unsigned short u[8]; short8 v; } cv;
    cv.u[0] = f2bf(a.x); cv.u[1] = f2bf(a.y); cv.u[2] = f2bf(a.z); cv.u[3] = f2bf(a.w);
    cv.u[4] = f2bf(b.x); cv.u[5] = f2bf(b.y); cv.u[6] = f2bf(b.z); cv.u[7] = f2bf(b.w);
    *reinterpret_cast<short8*>((unsigned short*)web + i0) = cv.v;
}

// ---------------- kernel 2b: enc fp32 -> bf16 ----------------
__global__ __launch_bounds__(256) void conv_enc(const float* __restrict__ src,
                                                __hip_bfloat16* __restrict__ dst) {
    size_t i0 = ((size_t)blockIdx.x * 256 + threadIdx.x) * 8;
    const float4* s = reinterpret_cast<const float4*>(src + i0);
    float4 a = s[0], b = s[1];
    union { unsigned short u[8]; short8 v; } cv;
    cv.u[0] = f2bf(a.x); cv.u[1] = f2bf(a.y); cv.u[2] = f2bf(a.z); cv.u[3] = f2bf(a.w);
    cv.u[4] = f2bf(b.x); cv.u[5] = f2bf(b.y); cv.u[6] = f2bf(b.z); cv.u[7] = f2bf(b.w);
    *reinterpret_cast<short8*>((unsigned short*)dst + i0) = cv.v;
}

// ---------------- kernel 3: 8-phase 256x256 GEMM + fused tanh/score epilogue ----------------
// LDS map (bytes): A[par][half] = par*32768 + half*16384 ; B[par][half] = 65536 + same. 128KB.
// Swizzle involution within each 128B row: byte ^= ((row&7)<<4). Applied to global src + ds_read.
__global__ __launch_bounds__(512, 2) void gemm8(const __hip_bfloat16* __restrict__ encb,
                                                const __hip_bfloat16* __restrict__ web,
                                                const float* __restrict__ qv,
                                                const float* __restrict__ score_w,
                                                float* __restrict__ part) {
    __shared__ __align__(16) char pool[131072];

    int tid = threadIdx.x;
    int lane = tid & 63;
    int wid = tid >> 6;        // 0..7
    int wr = wid >> 2;         // 0..1  M half
    int wc = wid & 3;          // 0..3  N quarter

    // XCD-bijective swizzle: 512 blocks = 8 XCDs x 64; same-bm (A-panel) blocks contiguous per XCD
    int bid = blockIdx.x;
    int lin = (bid & 7) * 64 + (bid >> 3);
    int bm = lin >> 2;         // 0..127
    int bn = lin & 3;          // 0..3
    int m0 = bm * BM, n0 = bn * BN;

    // ---- staging thread constants (pre-swizzled global source) ----
    int srow = tid >> 3;                                   // 0..63
    int scolb = (((tid & 7) ^ ((tid >> 3) & 7)) << 4);     // swizzled byte col 0..127
    const char* eb = (const char*)encb;
    const char* wb = (const char*)web;

    auto STG = [&](const char* g, int ldsoff) {
        GLD16(g + (size_t)srow * 2048 + scolb, pool + ldsoff + wid * 1024);
        GLD16(g + (size_t)(srow + 64) * 2048 + scolb, pool + ldsoff + 8192 + wid * 1024);
    };
    auto APTR = [&](int kt, int h) { return eb + ((size_t)(m0 + h * 128) * HDIM + kt * BKT) * 2; };
    auto BPTR = [&](int kt, int h) { return wb + ((size_t)(n0 + h * 128) * HDIM + kt * BKT) * 2; };
    // LDS region offsets (compile-time par/half)
#define ALDS(par, h) ((par) * 32768 + (h) * 16384)
#define BLDS(par, h) (65536 + (par) * 32768 + (h) * 16384)

    // ---- fragment-read constants (swizzled ds_read addresses) ----
    int lq = lane & 15, lh = lane >> 4;
    int flip = (lane & 7) << 4;
    int pks0 = lq * 128 + ((lh * 16) ^ flip);
    int pks1 = lq * 128 + (((64 + lh * 16)) ^ flip);
    int aFB = wr * 16384;                                   // + par*32768
    int bFB = 65536 + (wc >> 1) * 16384 + (wc & 1) * 8192;  // + par*32768

    f32x4 acc[8][4];
#pragma unroll
    for (int i = 0; i < 8; i++)
#pragma unroll
        for (int j = 0; j < 4; j++) acc[i][j] = (f32x4)0.f;
    short8 br[4][2];

#define RD8(off) (*reinterpret_cast<const short8*>(pool + (off)))

    // phase: reads (B full at Q==0 -> regs; A quarter Q) | stage | barrier | 16 MFMA | [vmcnt] barrier
#define PHASE(Q, PAR, STAGE_STMT, PRE_CLOSE)                                              \
    {                                                                                     \
        if ((Q) == 0) {                                                                   \
            _Pragma("unroll") for (int nj = 0; nj < 4; ++nj) {                            \
                br[nj][0] = RD8(bFB + (PAR) * 32768 + nj * 2048 + pks0);                  \
                br[nj][1] = RD8(bFB + (PAR) * 32768 + nj * 2048 + pks1);                  \
            }                                                                             \
        }                                                                                 \
        short8 a0k0 = RD8(aFB + (PAR) * 32768 + (2 * (Q)) * 2048 + pks0);                 \
        short8 a0k1 = RD8(aFB + (PAR) * 32768 + (2 * (Q)) * 2048 + pks1);                 \
        short8 a1k0 = RD8(aFB + (PAR) * 32768 + (2 * (Q) + 1) * 2048 + pks0);             \
        short8 a1k1 = RD8(aFB + (PAR) * 32768 + (2 * (Q) + 1) * 2048 + pks1);             \
        STAGE_STMT;                                                                       \
        __builtin_amdgcn_s_barrier();                                                     \
        __builtin_amdgcn_s_setprio(1);                                                    \
        _Pragma("unroll") for (int nj = 0; nj < 4; ++nj) {                                \
            acc[2 * (Q)][nj] = __builtin_amdgcn_mfma_f32_16x16x32_bf16(a0k0, br[nj][0], acc[2 * (Q)][nj], 0, 0, 0); \
            acc[2 * (Q)][nj] = __builtin_amdgcn_mfma_f32_16x16x32_bf16(a0k1, br[nj][1], acc[2 * (Q)][nj], 0, 0, 0); \
            acc[2 * (Q) + 1][nj] = __builtin_amdgcn_mfma_f32_16x16x32_bf16(a1k0, br[nj][0], acc[2 * (Q) + 1][nj], 0, 0, 0); \
            acc[2 * (Q) + 1][nj] = __builtin_amdgcn_mfma_f32_16x16x32_bf16(a1k1, br[nj][1], acc[2 * (Q) + 1][nj], 0, 0, 0); \
        }                                                                                 \
        __builtin_amdgcn_s_setprio(0);                                                    \
        PRE_CLOSE;                                                                        \
        __builtin_amdgcn_s_barrier();                                                     \
        __builtin_amdgcn_sched_barrier(0);                                                \
    }

    // ---- prologue: stage B(0), A(0), B(1); land tile 0 (oldest 8 loads) ----
    STG(BPTR(0, 0), BLDS(0, 0));
    STG(BPTR(0, 1), BLDS(0, 1));
    STG(APTR(0, 0), ALDS(0, 0));
    STG(APTR(0, 1), ALDS(0, 1));
    STG(BPTR(1, 0), BLDS(1, 0));
    STG(BPTR(1, 1), BLDS(1, 1));
    VMC(4);
    __builtin_amdgcn_s_barrier();
    __builtin_amdgcn_sched_barrier(0);

    // ---- main loop: iters J=0..6 (tiles 2J,2J+1), steady staging 2 tiles ahead ----
#pragma unroll 1
    for (int J = 0; J < 7; ++J) {
        int k1 = 2 * J + 1;
        PHASE(0, 0, STG(APTR(k1, 0), ALDS(1, 0)), );
        PHASE(1, 0, STG(APTR(k1, 1), ALDS(1, 1)), );
        PHASE(2, 0, STG(BPTR(k1 + 1, 0), BLDS(0, 0)), );
        PHASE(3, 0, STG(BPTR(k1 + 1, 1), BLDS(0, 1)), VMC(4));   // lands A(k1), B(k1)
        PHASE(0, 1, STG(APTR(k1 + 1, 0), ALDS(0, 0)), );
        PHASE(1, 1, STG(APTR(k1 + 1, 1), ALDS(0, 1)), );
        PHASE(2, 1, STG(BPTR(k1 + 2, 0), BLDS(1, 0)), );
        PHASE(3, 1, STG(BPTR(k1 + 2, 1), BLDS(1, 1)), VMC(4));   // lands A(k0+2), B(k0+2)
    }
    // ---- peeled last iter (tiles 14,15): stage only A(15); drain at P4 ----
    PHASE(0, 0, STG(APTR(15, 0), ALDS(1, 0)), );
    PHASE(1, 0, STG(APTR(15, 1), ALDS(1, 1)), );
    PHASE(2, 0, , );
    PHASE(3, 0, , VMC(0));
    PHASE(0, 1, , );
    PHASE(1, 1, , );
    PHASE(2, 1, , );
    PHASE(3, 1, , );

    // ---- fused epilogue (aliases pool) ----
    float* q_lds = reinterpret_cast<float*>(pool);            // [16][256]
    float* sc_lds = reinterpret_cast<float*>(pool + 16384);   // [256]
    float* eng = reinterpret_cast<float*>(pool + 17408);      // [4][256]
    {
        int qb = tid >> 5;            // 0..15
        int kl = (tid & 31) * 8;      // 0..248
        const float4* src = reinterpret_cast<const float4*>(qv + (size_t)qb * HDIM + n0 + kl);
        float4 v0 = src[0], v1 = src[1];
        *reinterpret_cast<float4*>(&q_lds[qb * 256 + kl]) = v0;
        *reinterpret_cast<float4*>(&q_lds[qb * 256 + kl + 4]) = v1;
        if (tid < BN) sc_lds[tid] = score_w[n0 + tid];
    }
    __syncthreads();

#pragma unroll
    for (int mi = 0; mi < 8; ++mi) {
#pragma unroll
        for (int r = 0; r < 4; ++r) {
            int b = lh * 4 + r;       // row-within-16 == batch index
            float s = 0.f;
#pragma unroll
            for (int nj = 0; nj < 4; ++nj) {
                int kl = wc * 64 + nj * 16 + lq;
                float v = acc[mi][nj][r] + q_lds[b * 256 + kl];
                float t = 1.f - 2.f / (__expf(2.f * v) + 1.f);  // tanh(v)
                s += sc_lds[kl] * t;
            }
            for (int off = 1; off < 16; off <<= 1) s += __shfl_xor(s, off);
            if (lq == 0) eng[wc * 256 + wr * 128 + mi * 16 + b] = s;
        }
    }
    __syncthreads();
    if (tid < BM) {
        float s = eng[tid] + eng[256 + tid] + eng[512 + tid] + eng[768 + tid];
        part[(size_t)bn * M_TOT + m0 + tid] = s;
    }
#undef PHASE
#undef RD8
#undef ALDS
#undef BLDS
}

// ---------------- kernel 4: reduce partials + mask + softmax over S ----------------
__global__ __launch_bounds__(256) void softmax_kernel(const float* __restrict__ part,
                                                      const int* __restrict__ mask,
                                                      float* __restrict__ out) {
    int b = blockIdx.x;
    int tid = threadIdx.x;
    __shared__ float e_lds[SEQ];
    __shared__ float red[4], red2[4];
    int lane = tid & 63, wid = tid >> 6;
    float lmax = -3.4e38f;
    for (int it = 0; it < SEQ / 256; ++it) {
        int s = it * 256 + tid;
        size_t m = (size_t)s * BATCH + b;
        float e = 0.f;
#pragma unroll
        for (int c = 0; c < NBLK; c++) e += part[(size_t)c * M_TOT + m];
        if (mask[(size_t)b * SEQ + s]) e = -1e12f;
        e_lds[s] = e;
        lmax = fmaxf(lmax, e);
    }
    for (int off = 32; off; off >>= 1) lmax = fmaxf(lmax, __shfl_xor(lmax, off));
    if (lane == 0) red[wid] = lmax;
    __syncthreads();
    float gmax = fmaxf(fmaxf(red[0], red[1]), fmaxf(red[2], red[3]));
    float lsum = 0.f;
    for (int it = 0; it < SEQ / 256; ++it) {
        int s = it * 256 + tid;
        float p = __expf(e_lds[s] - gmax);
        e_lds[s] = p;
        lsum += p;
    }
    for (int off = 32; off; off >>= 1) lsum += __shfl_xor(lsum, off);
    if (lane == 0) red2[wid] = lsum;
    __syncthreads();
    float inv = 1.f / (red2[0] + red2[1] + red2[2] + red2[3]);
    for (int it = 0; it < SEQ / 256; ++it) {
        int s = it * 256 + tid;
        out[(size_t)b * SEQ + s] = e_lds[s] * inv;
    }
}

extern "C" void kernel_launch(void* const* d_in, const int* in_sizes, int n_in,
                              void* d_out, int out_size, void* d_ws, size_t ws_size,
                              hipStream_t stream) {
    const float* hidden   = (const float*)d_in[0];
    const float* enc      = (const float*)d_in[1];
    const int*   seq_mask = (const int*)d_in[2];
    const float* attn_w   = (const float*)d_in[3];
    const float* attn_b   = (const float*)d_in[4];
    const float* score_w  = (const float*)d_in[5];
    float* out = (float*)d_out;

    char* ws = (char*)d_ws;
    float* q = (float*)ws;                                        // 64 KB
    __hip_bfloat16* web = (__hip_bfloat16*)(ws + 65536);          // 2 MB
    float* part = (float*)(ws + 65536 + 2 * 1024 * 1024);         // 512 KB
    __hip_bfloat16* encb = (__hip_bfloat16*)(ws + 65536 + 3 * 1024 * 1024);  // 64 MB

    conv_enc<<<dim3((M_TOT * HDIM) / (8 * 256)), dim3(256), 0, stream>>>(enc, encb);
    conv_kernel<<<dim3((HDIM * HDIM) / (8 * 256)), dim3(256), 0, stream>>>(attn_w, web);
    qk_kernel<<<dim3(HDIM), dim3(256), 0, stream>>>(hidden, attn_w, attn_b, q);
    gemm8<<<dim3(NBLK * (M_TOT / BM)), dim3(512), 0, stream>>>(encb, web, q, score_w, part);
    softmax_kernel<<<dim3(BATCH), dim3(256), 0, stream>>>(part, seq_mask, out);
}